// Round 9
// baseline (713.503 us; speedup 1.0000x reference)
//
#include <hip/hip_runtime.h>
#include <cmath>
#include <cstdint>

// Instant-NGP hash encoding: N=2^20 points, D=3, 16 levels, F=2, T=2^19.
// v9: counting-sort (4096 cells) -> each thread encodes 8 LEVELS of one
// sorted point and scatter-stores a contiguous 64B half-row to out[orig].
// Sorting makes table reuse a small-window property, so 8 levels/thread no
// longer thrashes L2; amortizes sorted-reads 8x and kills the untranspose.

constexpr uint32_t kLog2T = 19;
constexpr uint32_t kMask  = (1u << kLog2T) - 1u;
constexpr uint32_t kP1    = 2654435761u;
constexpr uint32_t kP2    = 805459861u;
constexpr uint32_t kN     = 1u << 20;
constexpr uint32_t kL     = 16;
constexpr uint32_t kBins  = 4096;

typedef float v2f __attribute__((ext_vector_type(2)));
typedef float v4f __attribute__((ext_vector_type(4)));

__device__ __forceinline__ v2f sel_half(v4f q, uint32_t hi) {
    v2f lo; lo.x = q.x; lo.y = q.y;
    v2f h2; h2.x = q.z; h2.y = q.w;
    return hi ? h2 : lo;
}

__device__ __forceinline__ uint32_t cell_key(float x, float y, float z) {
    uint32_t qx = (uint32_t)(x * 16.0f); qx = qx > 15u ? 15u : qx;
    uint32_t qy = (uint32_t)(y * 16.0f); qy = qy > 15u ? 15u : qy;
    uint32_t qz = (uint32_t)(z * 16.0f); qz = qz > 15u ? 15u : qz;
    return (qz << 8) | (qy << 4) | qx;
}

// ---- sort pipeline -------------------------------------------------------

__global__ __launch_bounds__(1024) void ngp_hist_kernel(
    const float* __restrict__ inp, uint32_t* __restrict__ bins)
{
    __shared__ uint32_t h[kBins];
    const uint32_t t = threadIdx.x;
    for (uint32_t i = t; i < kBins; i += 1024u) h[i] = 0u;
    __syncthreads();
    const uint32_t base = blockIdx.x * 1024u * 16u;
    #pragma unroll 4
    for (uint32_t k = 0; k < 16u; ++k) {
        const uint32_t n = base + k * 1024u + t;
        float x = fminf(fmaxf(inp[n * 3u + 0u], 0.0f), 1.0f);
        float y = fminf(fmaxf(inp[n * 3u + 1u], 0.0f), 1.0f);
        float z = fminf(fmaxf(inp[n * 3u + 2u], 0.0f), 1.0f);
        atomicAdd(&h[cell_key(x, y, z)], 1u);
    }
    __syncthreads();
    for (uint32_t i = t; i < kBins; i += 1024u)
        if (h[i]) atomicAdd(&bins[i], h[i]);
}

__global__ __launch_bounds__(64) void ngp_scan_kernel(
    const uint32_t* __restrict__ bins, uint32_t* __restrict__ cursor)
{
    const uint32_t t = threadIdx.x;          // one wave; 64 bins per lane
    uint32_t s = 0u;
    for (uint32_t i = 0; i < 64u; ++i) s += bins[t * 64u + i];
    uint32_t pre = s;
    for (int d = 1; d < 64; d <<= 1) {
        uint32_t u = __shfl_up(pre, d);
        if ((int)t >= d) pre += u;
    }
    pre -= s;                                 // exclusive prefix of chunk
    for (uint32_t i = 0; i < 64u; ++i) {
        cursor[t * 64u + i] = pre;
        pre += bins[t * 64u + i];
    }
}

__global__ __launch_bounds__(256) void ngp_scatter_kernel(
    const float* __restrict__ inp, uint32_t* __restrict__ cursor,
    v4f* __restrict__ sorted)
{
    const uint32_t n = blockIdx.x * 256u + threadIdx.x;
    float x = fminf(fmaxf(inp[n * 3u + 0u], 0.0f), 1.0f);
    float y = fminf(fmaxf(inp[n * 3u + 1u], 0.0f), 1.0f);
    float z = fminf(fmaxf(inp[n * 3u + 2u], 0.0f), 1.0f);
    const uint32_t key = cell_key(x, y, z);
    const uint32_t pos = atomicAdd(&cursor[key], 1u);
    v4f s; s.x = x; s.y = y; s.z = z; s.w = __uint_as_float(n);
    sorted[pos] = s;
}

// ---- encode: 8 levels per thread, direct 64B scatter-store ---------------

template <uint32_t BASE>
__global__ __launch_bounds__(256) void ngp_encode8_kernel(
    const v4f* __restrict__ sorted,     // [N] {x,y,z,orig}
    const v2f* __restrict__ tbl2,       // [16 * 2^19]
    v4f* __restrict__ out4,             // [N][8]
    unsigned long long pk0, unsigned long long pk1,
    unsigned long long pk2, unsigned long long pk3)
{
    const uint32_t j = blockIdx.x * 256u + threadIdx.x;
    const v4f s = sorted[j];            // pre-clamped
    const uint32_t orig = __float_as_uint(s.w);

    v2f acc[8];

    #pragma unroll
    for (uint32_t i = 0; i < 8u; ++i) {
        const uint32_t l = BASE + i;
        const unsigned long long pk = (l < 8u) ? ((l < 4u) ? pk0 : pk1)
                                               : ((l < 12u) ? pk2 : pk3);
        const float r = (float)((uint32_t)(pk >> ((l & 3u) * 16u)) & 0xFFFFu);

        const float px = s.x * r, py = s.y * r, pz = s.z * r;
        const float fx = floorf(px), fy = floorf(py), fz = floorf(pz);
        const float wx = px - fx, wy = py - fy, wz = pz - fz;

        const uint32_t xi  = (uint32_t)(int)fx;
        const uint32_t xi1 = xi + 1u;
        const uint32_t yi  = (uint32_t)(int)fy;
        const uint32_t zi  = (uint32_t)(int)fz;

        const uint32_t hy0 = yi * kP1, hy1 = hy0 + kP1;
        const uint32_t hz0 = zi * kP2, hz1 = hz0 + kP2;
        const uint32_t hyz00 = hy0 ^ hz0, hyz01 = hy0 ^ hz1;
        const uint32_t hyz10 = hy1 ^ hz0, hyz11 = hy1 ^ hz1;

        const uint32_t i000 = (xi  ^ hyz00) & kMask, i100 = (xi1 ^ hyz00) & kMask;
        const uint32_t i001 = (xi  ^ hyz01) & kMask, i101 = (xi1 ^ hyz01) & kMask;
        const uint32_t i010 = (xi  ^ hyz10) & kMask, i110 = (xi1 ^ hyz10) & kMask;
        const uint32_t i011 = (xi  ^ hyz11) & kMask, i111 = (xi1 ^ hyz11) & kMask;

        const v2f* tl2 = tbl2 + ((size_t)l << kLog2T);
        const v4f* tl4 = (const v4f*)tl2;

        // pair loads: cover both x-corners when xi even (prime_x == 1)
        const v4f q00 = tl4[i000 >> 1];
        const v4f q01 = tl4[i001 >> 1];
        const v4f q10 = tl4[i010 >> 1];
        const v4f q11 = tl4[i011 >> 1];

        v2f f000 = sel_half(q00, i000 & 1u), f100 = sel_half(q00, (i000 & 1u) ^ 1u);
        v2f f001 = sel_half(q01, i001 & 1u), f101 = sel_half(q01, (i001 & 1u) ^ 1u);
        v2f f010 = sel_half(q10, i010 & 1u), f110 = sel_half(q10, (i010 & 1u) ^ 1u);
        v2f f011 = sel_half(q11, i011 & 1u), f111 = sel_half(q11, (i011 & 1u) ^ 1u);

        if (xi & 1u) {   // odd xi: partner corner = exact 8B gather
            f100 = tl2[i100];
            f101 = tl2[i101];
            f110 = tl2[i110];
            f111 = tl2[i111];
        }

        const float wx1w = wx, wx0w = 1.0f - wx;
        const float wy1w = wy, wy0w = 1.0f - wy;
        const float wz1w = wz, wz0w = 1.0f - wz;
        const float wyz00w = wy0w * wz0w, wyz01w = wy0w * wz1w;
        const float wyz10w = wy1w * wz0w, wyz11w = wy1w * wz1w;

        float acc0 = 0.0f, acc1 = 0.0f;
#define NGP_ACC(F, W)                         \
        acc0 = fmaf((W), (F).x, acc0);        \
        acc1 = fmaf((W), (F).y, acc1);
        NGP_ACC(f000, wx0w * wyz00w) NGP_ACC(f100, wx1w * wyz00w)
        NGP_ACC(f001, wx0w * wyz01w) NGP_ACC(f101, wx1w * wyz01w)
        NGP_ACC(f010, wx0w * wyz10w) NGP_ACC(f110, wx1w * wyz10w)
        NGP_ACC(f011, wx0w * wyz11w) NGP_ACC(f111, wx1w * wyz11w)
#undef NGP_ACC
        acc[i].x = acc0;
        acc[i].y = acc1;
    }

    // one contiguous 64B half-row store (sector-aligned)
    #pragma unroll
    for (uint32_t k = 0; k < 4u; ++k) {
        v4f o;
        o.x = acc[2u * k].x;     o.y = acc[2u * k].y;
        o.z = acc[2u * k + 1].x; o.w = acc[2u * k + 1].y;
        __builtin_nontemporal_store(o, out4 + orig * 8u + (BASE / 2u) + k);
    }
}

// ---- fallback (no/small ws): direct strided, unsorted --------------------

__global__ __launch_bounds__(256) void ngp_encode_direct_kernel(
    const float* __restrict__ inp, const v2f* __restrict__ tbl2,
    v2f* __restrict__ dst,
    unsigned long long pk0, unsigned long long pk1,
    unsigned long long pk2, unsigned long long pk3)
{
    const uint32_t b = blockIdx.x;
    const uint32_t l = b >> 12;
    const uint32_t n = ((b & 4095u) << 8) + threadIdx.x;
    unsigned long long pk = (l < 8u) ? ((l < 4u) ? pk0 : pk1)
                                     : ((l < 12u) ? pk2 : pk3);
    const float r = (float)((uint32_t)(pk >> ((l & 3u) * 16u)) & 0xFFFFu);
    float x = fminf(fmaxf(inp[n * 3u + 0u], 0.0f), 1.0f);
    float y = fminf(fmaxf(inp[n * 3u + 1u], 0.0f), 1.0f);
    float z = fminf(fmaxf(inp[n * 3u + 2u], 0.0f), 1.0f);
    const float px = x * r, py = y * r, pz = z * r;
    const float fx = floorf(px), fy = floorf(py), fz = floorf(pz);
    const float wx = px - fx, wy = py - fy, wz = pz - fz;
    const uint32_t xi = (uint32_t)(int)fx, yi = (uint32_t)(int)fy, zi = (uint32_t)(int)fz;
    const uint32_t hy0 = yi * kP1, hy1 = hy0 + kP1;
    const uint32_t hz0 = zi * kP2, hz1 = hz0 + kP2;
    const uint32_t lb2 = l << kLog2T;
    float acc0 = 0.0f, acc1 = 0.0f;
#define NGP_C(HX, HY, HZ, W)                                        \
    {                                                               \
        uint32_t h = ((HX) ^ (HY) ^ (HZ)) & kMask;                  \
        v2f f = tbl2[lb2 + h];                                      \
        acc0 = fmaf((W), f.x, acc0); acc1 = fmaf((W), f.y, acc1);   \
    }
    const float wxa = 1.0f - wx, wya = 1.0f - wy, wza = 1.0f - wz;
    NGP_C(xi,      hy0, hz0, wxa * wya * wza) NGP_C(xi + 1u, hy0, hz0, wx * wya * wza)
    NGP_C(xi,      hy0, hz1, wxa * wya * wz ) NGP_C(xi + 1u, hy0, hz1, wx * wya * wz )
    NGP_C(xi,      hy1, hz0, wxa * wy  * wza) NGP_C(xi + 1u, hy1, hz0, wx * wy  * wza)
    NGP_C(xi,      hy1, hz1, wxa * wy  * wz ) NGP_C(xi + 1u, hy1, hz1, wx * wy  * wz )
#undef NGP_C
    v2f res; res.x = acc0; res.y = acc1;
    dst[n * kL + l] = res;
}

extern "C" void kernel_launch(void* const* d_in, const int* in_sizes, int n_in,
                              void* d_out, int out_size, void* d_ws, size_t ws_size,
                              hipStream_t stream)
{
    const float* inp = (const float*)d_in[0];
    const v2f* tbl2  = (const v2f*)d_in[1];

    // numpy-exact resolution table (host libm float64 chain)
    double b = std::exp((std::log(512.0) - std::log(16.0)) / 15.0);
    unsigned long long pk[4] = {0ull, 0ull, 0ull, 0ull};
    for (int k = 0; k < 16; ++k) {
        double v;
        if (k == 0)      v = 1.0;
        else if (k == 1) v = b;
        else if (k == 2) v = b * b;
        else             v = std::pow(b, (double)k);
        unsigned long long ri = (unsigned long long)std::floor(16.0 * v);
        pk[k >> 2] |= (ri & 0xFFFFull) << ((k & 3) * 16);
    }

    // ws layout: sorted v4f[N] (16MB) | bins u32[4096] | cursor u32[4096]
    const size_t offSorted = 0;
    const size_t offBins   = (size_t)kN * sizeof(v4f);
    const size_t offCursor = offBins + kBins * sizeof(uint32_t);
    const size_t need      = offCursor + kBins * sizeof(uint32_t);

    if (ws_size >= need) {
        char* w = (char*)d_ws;
        v4f*      sorted = (v4f*)(w + offSorted);
        uint32_t* bins   = (uint32_t*)(w + offBins);
        uint32_t* cursor = (uint32_t*)(w + offCursor);

        hipMemsetAsync(bins, 0, kBins * sizeof(uint32_t), stream);
        hipLaunchKernelGGL(ngp_hist_kernel, dim3(64), dim3(1024), 0, stream, inp, bins);
        hipLaunchKernelGGL(ngp_scan_kernel, dim3(1), dim3(64), 0, stream, bins, cursor);
        hipLaunchKernelGGL(ngp_scatter_kernel, dim3(kN / 256u), dim3(256), 0, stream,
                           inp, cursor, sorted);

        hipLaunchKernelGGL((ngp_encode8_kernel<0>), dim3(kN / 256u), dim3(256), 0, stream,
                           sorted, tbl2, (v4f*)d_out, pk[0], pk[1], pk[2], pk[3]);
        hipLaunchKernelGGL((ngp_encode8_kernel<8>), dim3(kN / 256u), dim3(256), 0, stream,
                           sorted, tbl2, (v4f*)d_out, pk[0], pk[1], pk[2], pk[3]);
    } else {
        hipLaunchKernelGGL(ngp_encode_direct_kernel, dim3((kN * kL) / 256u), dim3(256), 0, stream,
                           inp, tbl2, (v2f*)d_out, pk[0], pk[1], pk[2], pk[3]);
    }
}